// Round 5
// baseline (485.418 us; speedup 1.0000x reference)
//
#include <hip/hip_runtime.h>

#define F 128
#define NEG_SLOPE 0.01f
#define NPASS 8

typedef _Float16 half8_t __attribute__((ext_vector_type(8)));
typedef float f32x4 __attribute__((ext_vector_type(4)));

// ---------------- graph prep ----------------

__global__ __launch_bounds__(256) void deg_kernel(const int* __restrict__ dst,
                                                  int* __restrict__ deg, int E) {
    int e = blockIdx.x * 256 + threadIdx.x;
    if (e < E) atomicAdd(&deg[dst[e]], 1);
}

// scan1 also produces dis = rsqrt(deg+1)
__global__ __launch_bounds__(1024) void scan1(const int* __restrict__ deg,
                                              int* __restrict__ offs,
                                              int* __restrict__ bsum,
                                              float* __restrict__ dis, int n) {
    __shared__ int tmp[1024];
    int tid = threadIdx.x;
    int idx = blockIdx.x * 1024 + tid;
    int v = (idx < n) ? deg[idx] : 0;
    if (idx < n) dis[idx] = rsqrtf((float)v + 1.0f);
    int run = v;
    tmp[tid] = v;
    __syncthreads();
    for (int off = 1; off < 1024; off <<= 1) {
        int add = (tid >= off) ? tmp[tid - off] : 0;
        __syncthreads();
        run += add;
        tmp[tid] = run;
        __syncthreads();
    }
    if (idx < n) offs[idx] = run - v;          // exclusive, pre-base
    if (tid == 1023) bsum[blockIdx.x] = run;   // block total
}

__global__ __launch_bounds__(128) void scan2(const int* __restrict__ bsum,
                                             int* __restrict__ bbase, int nb) {
    __shared__ int tmp[128];
    int tid = threadIdx.x;
    int v0 = (tid < nb) ? bsum[tid] : 0;
    int v = v0;
    tmp[tid] = v;
    __syncthreads();
    for (int off = 1; off < 128; off <<= 1) {
        int add = (tid >= off) ? tmp[tid - off] : 0;
        __syncthreads();
        v += add;
        tmp[tid] = v;
        __syncthreads();
    }
    if (tid < nb) bbase[tid] = v - v0;  // exclusive
}

__global__ __launch_bounds__(1024) void scan3(int* __restrict__ offs,
                                              const int* __restrict__ bbase,
                                              int* __restrict__ cursor, int n) {
    int idx = blockIdx.x * 1024 + threadIdx.x;
    if (idx < n) {
        int o = offs[idx] + bbase[blockIdx.x];
        offs[idx] = o;
        cursor[idx] = o;
    }
}

// CSR fill, dst-range partitioned: pass k writes only positions for
// dst in [lo,hi) -> a contiguous ~1.6MB window that stays L2-resident,
// so the scattered 8B stores merge before writeback (vs 64B/line x 1.6M).
__global__ __launch_bounds__(256) void fill_pass(const int* __restrict__ src,
                                                 const int* __restrict__ dst,
                                                 const float* __restrict__ dis,
                                                 int* __restrict__ cursor,
                                                 int2* __restrict__ edges,
                                                 int E, int lo, int hi) {
    int e = blockIdx.x * 256 + threadIdx.x;
    if (e < E) {
        int d = dst[e];
        if (d >= lo && d < hi) {
            int s = src[e];
            int pos = atomicAdd(&cursor[d], 1);
            edges[pos] = make_int2(s, __float_as_int(dis[s] * dis[d]));
        }
    }
}

// ---------------- W1+W2 fp32 -> fp16 in one launch ----------------

__global__ __launch_bounds__(256) void cvt_w(const float* __restrict__ W1,
                                             const float* __restrict__ W2,
                                             _Float16* __restrict__ W1h,
                                             _Float16* __restrict__ W2h) {
    int i = blockIdx.x * 256 + threadIdx.x;       // 0 .. 8191 (2 * 128*128/4)
    const int n4 = F * F / 4;
    const float* in = (i < n4) ? W1 : W2;
    _Float16* out = (i < n4) ? W1h : W2h;
    int j = (i < n4) ? i : i - n4;
    float4 v = ((const float4*)in)[j];
    half8_t h;  // only low 4 used
    h[0] = (_Float16)v.x; h[1] = (_Float16)v.y;
    h[2] = (_Float16)v.z; h[3] = (_Float16)v.w;
    *(int2*)&((_Float16*)out)[j * 4] = *(int2*)&h;
}

// ---------------- GEMM: out = A @ W.T via f16 MFMA ----------------
// Per wave: one 16-row tile x full 128 cols; W fragments register-resident.
// Layouts: A[m=lane&15][k=quad*8+j]; B[n=lane&15][k=quad*8+j] (=W[n][k]);
// C/D: col=lane&15, row=quad*4+reg.

__device__ __forceinline__ void gemm_core(const half8_t afrag[4],
                                          const _Float16* __restrict__ Wh,
                                          int m, int quad,
                                          _Float16* __restrict__ orow) {
    f32x4 acc[8];
#pragma unroll
    for (int t = 0; t < 8; ++t) acc[t] = (f32x4){0.f, 0.f, 0.f, 0.f};
#pragma unroll
    for (int c = 0; c < 4; ++c) {
#pragma unroll
        for (int t = 0; t < 8; ++t) {
            half8_t bfrag = *(const half8_t*)&Wh[(t * 16 + m) * F + c * 32 + quad * 8];
            acc[t] = __builtin_amdgcn_mfma_f32_16x16x32_f16(afrag[c], bfrag, acc[t],
                                                            0, 0, 0);
        }
    }
#pragma unroll
    for (int t = 0; t < 8; ++t)
#pragma unroll
        for (int r = 0; r < 4; ++r)
            orow[(quad * 4 + r) * F + t * 16 + m] = (_Float16)acc[t][r];
}

// layer-1 variant: A is fp32 (reads x directly, converts in-register)
__global__ __launch_bounds__(256) void gemm_a32(const float* __restrict__ A,
                                                const _Float16* __restrict__ Wh,
                                                _Float16* __restrict__ out,
                                                int ntiles) {
    int wave = threadIdx.x >> 6;
    int lane = threadIdx.x & 63;
    int tile = blockIdx.x * 4 + wave;
    if (tile >= ntiles) return;
    int m = lane & 15, quad = lane >> 4;
    const float* arow = A + (size_t)tile * 16 * F;
    half8_t afrag[4];
#pragma unroll
    for (int c = 0; c < 4; ++c) {
        float4 t0 = *(const float4*)&arow[m * F + c * 32 + quad * 8];
        float4 t1 = *(const float4*)&arow[m * F + c * 32 + quad * 8 + 4];
        afrag[c][0] = (_Float16)t0.x; afrag[c][1] = (_Float16)t0.y;
        afrag[c][2] = (_Float16)t0.z; afrag[c][3] = (_Float16)t0.w;
        afrag[c][4] = (_Float16)t1.x; afrag[c][5] = (_Float16)t1.y;
        afrag[c][6] = (_Float16)t1.z; afrag[c][7] = (_Float16)t1.w;
    }
    gemm_core(afrag, Wh, m, quad, out + (size_t)tile * 16 * F);
}

// layer-2 variant: A is fp16
__global__ __launch_bounds__(256) void gemm_a16(const _Float16* __restrict__ A,
                                                const _Float16* __restrict__ Wh,
                                                _Float16* __restrict__ out,
                                                int ntiles) {
    int wave = threadIdx.x >> 6;
    int lane = threadIdx.x & 63;
    int tile = blockIdx.x * 4 + wave;
    if (tile >= ntiles) return;
    int m = lane & 15, quad = lane >> 4;
    const _Float16* arow = A + (size_t)tile * 16 * F;
    half8_t afrag[4];
#pragma unroll
    for (int c = 0; c < 4; ++c)
        afrag[c] = *(const half8_t*)&arow[m * F + c * 32 + quad * 8];
    gemm_core(afrag, Wh, m, quad, out + (size_t)tile * 16 * F);
}

// ---------------- aggregation ----------------
// One wave per node. 16 lanes x half8 (16B) cover one 256B row; 4 edge
// groups per wave -> each gather instruction moves 4 rows (1KB/wave-inst).

#define AGG_BODY(H8)                                                           \
    int node = blockIdx.x * 4 + (threadIdx.x >> 6);                            \
    int lane = threadIdx.x & 63;                                               \
    if (node >= n) return;                                                     \
    int g = lane >> 4;                                                         \
    int fo = lane & 15;                                                        \
    int beg = offs[node];                                                      \
    int end = (node + 1 < n) ? offs[node + 1] : E;                             \
    float acc[8];                                                              \
    _Pragma("unroll") for (int j = 0; j < 8; ++j) acc[j] = 0.f;                \
    for (int e = beg; e < end; e += 8) {                                       \
        int i0 = e + g, i1 = e + 4 + g;                                        \
        int2 e0 = edges[i0 < end ? i0 : end - 1];                              \
        int2 e1 = edges[i1 < end ? i1 : end - 1];                              \
        half8_t a0 = H8[(size_t)e0.x * 16 + fo];                               \
        half8_t a1 = H8[(size_t)e1.x * 16 + fo];                               \
        float w0 = (i0 < end) ? __int_as_float(e0.y) : 0.f;                    \
        float w1 = (i1 < end) ? __int_as_float(e1.y) : 0.f;                    \
        _Pragma("unroll") for (int j = 0; j < 8; ++j)                          \
            acc[j] += w0 * (float)a0[j] + w1 * (float)a1[j];                   \
    }                                                                          \
    _Pragma("unroll") for (int j = 0; j < 8; ++j) {                            \
        acc[j] += __shfl_xor(acc[j], 16);                                      \
        acc[j] += __shfl_xor(acc[j], 32);                                      \
    }                                                                          \
    if (lane >= 16) return;                                                    \
    float di = dis[node];                                                      \
    float sw = di * di;                                                        \
    half8_t hv = H8[(size_t)node * 16 + fo];                                   \
    float4 b0 = ((const float4*)bias)[fo * 2];                                 \
    float4 b1v = ((const float4*)bias)[fo * 2 + 1];                            \
    acc[0] += sw * (float)hv[0] + b0.x;  acc[1] += sw * (float)hv[1] + b0.y;   \
    acc[2] += sw * (float)hv[2] + b0.z;  acc[3] += sw * (float)hv[3] + b0.w;   \
    acc[4] += sw * (float)hv[4] + b1v.x; acc[5] += sw * (float)hv[5] + b1v.y;  \
    acc[6] += sw * (float)hv[6] + b1v.z; acc[7] += sw * (float)hv[7] + b1v.w;  \
    _Pragma("unroll") for (int j = 0; j < 8; ++j)                              \
        acc[j] = (acc[j] > 0.f) ? acc[j] : acc[j] * NEG_SLOPE;

// layer-1: writes fp16 (feeds next GEMM)
__global__ __launch_bounds__(256) void agg_to_h(const half8_t* __restrict__ h8,
                                                const float* __restrict__ dis,
                                                const float* __restrict__ bias,
                                                const int2* __restrict__ edges,
                                                const int* __restrict__ offs,
                                                half8_t* __restrict__ out,
                                                int n, int E) {
    AGG_BODY(h8)
    half8_t o;
#pragma unroll
    for (int j = 0; j < 8; ++j) o[j] = (_Float16)acc[j];
    out[(size_t)node * 16 + fo] = o;
}

// layer-2: writes fp32 (final output)
__global__ __launch_bounds__(256) void agg_to_f(const half8_t* __restrict__ h8,
                                                const float* __restrict__ dis,
                                                const float* __restrict__ bias,
                                                const int2* __restrict__ edges,
                                                const int* __restrict__ offs,
                                                float* __restrict__ out,
                                                int n, int E) {
    AGG_BODY(h8)
    float4 o0 = make_float4(acc[0], acc[1], acc[2], acc[3]);
    float4 o1 = make_float4(acc[4], acc[5], acc[6], acc[7]);
    ((float4*)out)[(size_t)node * 32 + fo * 2] = o0;
    ((float4*)out)[(size_t)node * 32 + fo * 2 + 1] = o1;
}

// ---------------- launch ----------------

static inline size_t alup(size_t x) { return (x + 255) & ~(size_t)255; }

extern "C" void kernel_launch(void* const* d_in, const int* in_sizes, int n_in,
                              void* d_out, int out_size, void* d_ws, size_t ws_size,
                              hipStream_t stream) {
    const float* x  = (const float*)d_in[0];
    const int*   ei = (const int*)d_in[1];
    const float* W1 = (const float*)d_in[2];
    const float* b1 = (const float*)d_in[3];
    const float* W2 = (const float*)d_in[4];
    const float* b2 = (const float*)d_in[5];
    float* out = (float*)d_out;

    const int N = in_sizes[0] / F;    // 100000
    const int E = in_sizes[1] / 2;    // 1600000
    const int* src = ei;
    const int* dst = ei + E;

    char* p = (char*)d_ws;
    int*      deg    = (int*)p;      p += alup((size_t)N * 4);
    int*      offs   = (int*)p;      p += alup((size_t)N * 4);
    int*      cursor = (int*)p;      p += alup((size_t)N * 4);
    int*      bsum   = (int*)p;      p += alup(128 * 4);
    int*      bbase  = (int*)p;      p += alup(128 * 4);
    float*    dis    = (float*)p;    p += alup((size_t)N * 4);
    int2*     edges  = (int2*)p;     p += alup((size_t)E * 8);
    _Float16* g      = (_Float16*)p; p += alup((size_t)N * F * 2);  // agg out L1
    _Float16* hh     = (_Float16*)p; p += alup((size_t)N * F * 2);  // gemm out
    _Float16* W1h    = (_Float16*)p; p += alup((size_t)F * F * 2);
    _Float16* W2h    = (_Float16*)p; p += alup((size_t)F * F * 2);

    const int nb = (N + 1023) / 1024;      // 98
    const int ntiles = (N + 15) / 16;      // 6250
    const int gemm_grid = (ntiles + 3) / 4;

    hipMemsetAsync(deg, 0, (size_t)N * 4, stream);
    deg_kernel<<<(E + 255) / 256, 256, 0, stream>>>(dst, deg, E);
    scan1<<<nb, 1024, 0, stream>>>(deg, offs, bsum, dis, N);
    scan2<<<1, 128, 0, stream>>>(bsum, bbase, nb);
    scan3<<<nb, 1024, 0, stream>>>(offs, bbase, cursor, N);
    cvt_w<<<(2 * F * F / 4 + 255) / 256, 256, 0, stream>>>(W1, W2, W1h, W2h);

    const int prange = (N + NPASS - 1) / NPASS;  // 12500
    for (int k = 0; k < NPASS; ++k) {
        int lo = k * prange;
        int hi = (lo + prange < N) ? lo + prange : N;
        fill_pass<<<(E + 255) / 256, 256, 0, stream>>>(src, dst, dis, cursor,
                                                       edges, E, lo, hi);
    }

    // layer 1: h = x @ W1.T (fp32 in, fp16 out), agg(+b1+lrelu) -> g (fp16)
    gemm_a32<<<gemm_grid, 256, 0, stream>>>(x, W1h, hh, ntiles);
    agg_to_h<<<(N + 3) / 4, 256, 0, stream>>>((const half8_t*)hh, dis, b1, edges,
                                              offs, (half8_t*)g, N, E);
    // layer 2: h = g @ W2.T (fp16), agg(+b2+lrelu) -> d_out (fp32)
    gemm_a16<<<gemm_grid, 256, 0, stream>>>(g, W2h, hh, ntiles);
    agg_to_f<<<(N + 3) / 4, 256, 0, stream>>>((const half8_t*)hh, dis, b2, edges,
                                              offs, out, N, E);
}

// Round 6
// 442.517 us; speedup vs baseline: 1.0969x; 1.0969x over previous
//
#include <hip/hip_runtime.h>

#define F 128
#define NEG_SLOPE 0.01f
#define NXCD 8

typedef _Float16 half8_t __attribute__((ext_vector_type(8)));
typedef float f32x4 __attribute__((ext_vector_type(4)));

// ---------------- graph prep ----------------

__global__ __launch_bounds__(256) void deg_kernel(const int* __restrict__ dst,
                                                  int* __restrict__ deg, int E) {
    int e = blockIdx.x * 256 + threadIdx.x;
    if (e < E) atomicAdd(&deg[dst[e]], 1);
}

// scan1 also produces dis = rsqrt(deg+1)
__global__ __launch_bounds__(1024) void scan1(const int* __restrict__ deg,
                                              int* __restrict__ offs,
                                              int* __restrict__ bsum,
                                              float* __restrict__ dis, int n) {
    __shared__ int tmp[1024];
    int tid = threadIdx.x;
    int idx = blockIdx.x * 1024 + tid;
    int v = (idx < n) ? deg[idx] : 0;
    if (idx < n) dis[idx] = rsqrtf((float)v + 1.0f);
    int run = v;
    tmp[tid] = v;
    __syncthreads();
    for (int off = 1; off < 1024; off <<= 1) {
        int add = (tid >= off) ? tmp[tid - off] : 0;
        __syncthreads();
        run += add;
        tmp[tid] = run;
        __syncthreads();
    }
    if (idx < n) offs[idx] = run - v;          // exclusive, pre-base
    if (tid == 1023) bsum[blockIdx.x] = run;   // block total
}

__global__ __launch_bounds__(128) void scan2(const int* __restrict__ bsum,
                                             int* __restrict__ bbase, int nb) {
    __shared__ int tmp[128];
    int tid = threadIdx.x;
    int v0 = (tid < nb) ? bsum[tid] : 0;
    int v = v0;
    tmp[tid] = v;
    __syncthreads();
    for (int off = 1; off < 128; off <<= 1) {
        int add = (tid >= off) ? tmp[tid - off] : 0;
        __syncthreads();
        v += add;
        tmp[tid] = v;
        __syncthreads();
    }
    if (tid < nb) bbase[tid] = v - v0;  // exclusive
}

__global__ __launch_bounds__(1024) void scan3(int* __restrict__ offs,
                                              const int* __restrict__ bbase,
                                              int* __restrict__ cursor, int n) {
    int idx = blockIdx.x * 1024 + threadIdx.x;
    if (idx < n) {
        int o = offs[idx] + bbase[blockIdx.x];
        offs[idx] = o;
        cursor[idx] = o;
    }
}

// CSR fill, XCD-grouped: block (k = blockIdx&7, chunk = blockIdx>>3) processes
// edge chunk, keeping only dst in partition k. Under round-robin workgroup
// dispatch all blocks with equal blockIdx%8 land on one XCD, so partition k's
// contiguous output window is written by a single XCD's L2 -> the 8B scattered
// stores merge into full lines before writeback (vs 64B/line x 1.6M edges).
// Pure perf heuristic: correctness holds for any dispatch mapping.
__global__ __launch_bounds__(256) void fill_xcd(const int* __restrict__ src,
                                                const int* __restrict__ dst,
                                                const float* __restrict__ dis,
                                                int* __restrict__ cursor,
                                                int2* __restrict__ edges,
                                                int E, int prange, int N) {
    int k = blockIdx.x & (NXCD - 1);
    int chunk = blockIdx.x >> 3;
    int lo = k * prange;
    int hi = lo + prange; if (hi > N) hi = N;
    int e = chunk * 256 + threadIdx.x;
    if (e < E) {
        int d = dst[e];
        if (d >= lo && d < hi) {
            int s = src[e];
            int pos = atomicAdd(&cursor[d], 1);
            edges[pos] = make_int2(s, __float_as_int(dis[s] * dis[d]));
        }
    }
}

// ---------------- W1+W2 fp32 -> fp16 in one launch ----------------

__global__ __launch_bounds__(256) void cvt_w(const float* __restrict__ W1,
                                             const float* __restrict__ W2,
                                             _Float16* __restrict__ W1h,
                                             _Float16* __restrict__ W2h) {
    int i = blockIdx.x * 256 + threadIdx.x;       // 0 .. 8191 (2 * 128*128/4)
    const int n4 = F * F / 4;
    const float* in = (i < n4) ? W1 : W2;
    _Float16* out = (i < n4) ? W1h : W2h;
    int j = (i < n4) ? i : i - n4;
    float4 v = ((const float4*)in)[j];
    half8_t h;  // only low 4 used
    h[0] = (_Float16)v.x; h[1] = (_Float16)v.y;
    h[2] = (_Float16)v.z; h[3] = (_Float16)v.w;
    *(int2*)&((_Float16*)out)[j * 4] = *(int2*)&h;
}

// ---------------- GEMM: out = A @ W.T via f16 MFMA ----------------
// Per wave: one 16-row tile x full 128 cols; W fragments register-resident.
// Layouts: A[m=lane&15][k=quad*8+j]; B[n=lane&15][k=quad*8+j] (=W[n][k]);
// C/D: col=lane&15, row=quad*4+reg.

__device__ __forceinline__ void gemm_core(const half8_t afrag[4],
                                          const _Float16* __restrict__ Wh,
                                          int m, int quad,
                                          _Float16* __restrict__ orow) {
    f32x4 acc[8];
#pragma unroll
    for (int t = 0; t < 8; ++t) acc[t] = (f32x4){0.f, 0.f, 0.f, 0.f};
#pragma unroll
    for (int c = 0; c < 4; ++c) {
#pragma unroll
        for (int t = 0; t < 8; ++t) {
            half8_t bfrag = *(const half8_t*)&Wh[(t * 16 + m) * F + c * 32 + quad * 8];
            acc[t] = __builtin_amdgcn_mfma_f32_16x16x32_f16(afrag[c], bfrag, acc[t],
                                                            0, 0, 0);
        }
    }
#pragma unroll
    for (int t = 0; t < 8; ++t)
#pragma unroll
        for (int r = 0; r < 4; ++r)
            orow[(quad * 4 + r) * F + t * 16 + m] = (_Float16)acc[t][r];
}

// layer-1 variant: A is fp32 (reads x directly, converts in-register)
__global__ __launch_bounds__(256) void gemm_a32(const float* __restrict__ A,
                                                const _Float16* __restrict__ Wh,
                                                _Float16* __restrict__ out,
                                                int ntiles) {
    int wave = threadIdx.x >> 6;
    int lane = threadIdx.x & 63;
    int tile = blockIdx.x * 4 + wave;
    if (tile >= ntiles) return;
    int m = lane & 15, quad = lane >> 4;
    const float* arow = A + (size_t)tile * 16 * F;
    half8_t afrag[4];
#pragma unroll
    for (int c = 0; c < 4; ++c) {
        float4 t0 = *(const float4*)&arow[m * F + c * 32 + quad * 8];
        float4 t1 = *(const float4*)&arow[m * F + c * 32 + quad * 8 + 4];
        afrag[c][0] = (_Float16)t0.x; afrag[c][1] = (_Float16)t0.y;
        afrag[c][2] = (_Float16)t0.z; afrag[c][3] = (_Float16)t0.w;
        afrag[c][4] = (_Float16)t1.x; afrag[c][5] = (_Float16)t1.y;
        afrag[c][6] = (_Float16)t1.z; afrag[c][7] = (_Float16)t1.w;
    }
    gemm_core(afrag, Wh, m, quad, out + (size_t)tile * 16 * F);
}

// layer-2 variant: A is fp16
__global__ __launch_bounds__(256) void gemm_a16(const _Float16* __restrict__ A,
                                                const _Float16* __restrict__ Wh,
                                                _Float16* __restrict__ out,
                                                int ntiles) {
    int wave = threadIdx.x >> 6;
    int lane = threadIdx.x & 63;
    int tile = blockIdx.x * 4 + wave;
    if (tile >= ntiles) return;
    int m = lane & 15, quad = lane >> 4;
    const _Float16* arow = A + (size_t)tile * 16 * F;
    half8_t afrag[4];
#pragma unroll
    for (int c = 0; c < 4; ++c)
        afrag[c] = *(const half8_t*)&arow[m * F + c * 32 + quad * 8];
    gemm_core(afrag, Wh, m, quad, out + (size_t)tile * 16 * F);
}

// ---------------- aggregation ----------------
// One wave per node. 16 lanes x half8 (16B) cover one 256B row; 4 edge
// groups per wave -> each gather instruction moves 4 rows (1KB/wave-inst).

#define AGG_BODY(H8)                                                           \
    int node = blockIdx.x * 4 + (threadIdx.x >> 6);                            \
    int lane = threadIdx.x & 63;                                               \
    if (node >= n) return;                                                     \
    int g = lane >> 4;                                                         \
    int fo = lane & 15;                                                        \
    int beg = offs[node];                                                      \
    int end = (node + 1 < n) ? offs[node + 1] : E;                             \
    float acc[8];                                                              \
    _Pragma("unroll") for (int j = 0; j < 8; ++j) acc[j] = 0.f;                \
    for (int e = beg; e < end; e += 8) {                                       \
        int i0 = e + g, i1 = e + 4 + g;                                        \
        int2 e0 = edges[i0 < end ? i0 : end - 1];                              \
        int2 e1 = edges[i1 < end ? i1 : end - 1];                              \
        half8_t a0 = H8[(size_t)e0.x * 16 + fo];                               \
        half8_t a1 = H8[(size_t)e1.x * 16 + fo];                               \
        float w0 = (i0 < end) ? __int_as_float(e0.y) : 0.f;                    \
        float w1 = (i1 < end) ? __int_as_float(e1.y) : 0.f;                    \
        _Pragma("unroll") for (int j = 0; j < 8; ++j)                          \
            acc[j] += w0 * (float)a0[j] + w1 * (float)a1[j];                   \
    }                                                                          \
    _Pragma("unroll") for (int j = 0; j < 8; ++j) {                            \
        acc[j] += __shfl_xor(acc[j], 16);                                      \
        acc[j] += __shfl_xor(acc[j], 32);                                      \
    }                                                                          \
    if (lane >= 16) return;                                                    \
    float di = dis[node];                                                      \
    float sw = di * di;                                                        \
    half8_t hv = H8[(size_t)node * 16 + fo];                                   \
    float4 b0 = ((const float4*)bias)[fo * 2];                                 \
    float4 b1v = ((const float4*)bias)[fo * 2 + 1];                            \
    acc[0] += sw * (float)hv[0] + b0.x;  acc[1] += sw * (float)hv[1] + b0.y;   \
    acc[2] += sw * (float)hv[2] + b0.z;  acc[3] += sw * (float)hv[3] + b0.w;   \
    acc[4] += sw * (float)hv[4] + b1v.x; acc[5] += sw * (float)hv[5] + b1v.y;  \
    acc[6] += sw * (float)hv[6] + b1v.z; acc[7] += sw * (float)hv[7] + b1v.w;  \
    _Pragma("unroll") for (int j = 0; j < 8; ++j)                              \
        acc[j] = (acc[j] > 0.f) ? acc[j] : acc[j] * NEG_SLOPE;

// layer-1: writes fp16 (feeds next GEMM)
__global__ __launch_bounds__(256) void agg_to_h(const half8_t* __restrict__ h8,
                                                const float* __restrict__ dis,
                                                const float* __restrict__ bias,
                                                const int2* __restrict__ edges,
                                                const int* __restrict__ offs,
                                                half8_t* __restrict__ out,
                                                int n, int E) {
    AGG_BODY(h8)
    half8_t o;
#pragma unroll
    for (int j = 0; j < 8; ++j) o[j] = (_Float16)acc[j];
    out[(size_t)node * 16 + fo] = o;
}

// layer-2: writes fp32 (final output)
__global__ __launch_bounds__(256) void agg_to_f(const half8_t* __restrict__ h8,
                                                const float* __restrict__ dis,
                                                const float* __restrict__ bias,
                                                const int2* __restrict__ edges,
                                                const int* __restrict__ offs,
                                                float* __restrict__ out,
                                                int n, int E) {
    AGG_BODY(h8)
    float4 o0 = make_float4(acc[0], acc[1], acc[2], acc[3]);
    float4 o1 = make_float4(acc[4], acc[5], acc[6], acc[7]);
    ((float4*)out)[(size_t)node * 32 + fo * 2] = o0;
    ((float4*)out)[(size_t)node * 32 + fo * 2 + 1] = o1;
}

// ---------------- launch ----------------

static inline size_t alup(size_t x) { return (x + 255) & ~(size_t)255; }

extern "C" void kernel_launch(void* const* d_in, const int* in_sizes, int n_in,
                              void* d_out, int out_size, void* d_ws, size_t ws_size,
                              hipStream_t stream) {
    const float* x  = (const float*)d_in[0];
    const int*   ei = (const int*)d_in[1];
    const float* W1 = (const float*)d_in[2];
    const float* b1 = (const float*)d_in[3];
    const float* W2 = (const float*)d_in[4];
    const float* b2 = (const float*)d_in[5];
    float* out = (float*)d_out;

    const int N = in_sizes[0] / F;    // 100000
    const int E = in_sizes[1] / 2;    // 1600000
    const int* src = ei;
    const int* dst = ei + E;

    char* p = (char*)d_ws;
    int*      deg    = (int*)p;      p += alup((size_t)N * 4);
    int*      offs   = (int*)p;      p += alup((size_t)N * 4);
    int*      cursor = (int*)p;      p += alup((size_t)N * 4);
    int*      bsum   = (int*)p;      p += alup(128 * 4);
    int*      bbase  = (int*)p;      p += alup(128 * 4);
    float*    dis    = (float*)p;    p += alup((size_t)N * 4);
    int2*     edges  = (int2*)p;     p += alup((size_t)E * 8);
    _Float16* g      = (_Float16*)p; p += alup((size_t)N * F * 2);  // agg out L1
    _Float16* hh     = (_Float16*)p; p += alup((size_t)N * F * 2);  // gemm out
    _Float16* W1h    = (_Float16*)p; p += alup((size_t)F * F * 2);
    _Float16* W2h    = (_Float16*)p; p += alup((size_t)F * F * 2);

    const int nb = (N + 1023) / 1024;      // 98
    const int ntiles = (N + 15) / 16;      // 6250
    const int gemm_grid = (ntiles + 3) / 4;
    const int nchunks = (E + 255) / 256;   // 6250
    const int prange = (N + NXCD - 1) / NXCD;  // 12500

    hipMemsetAsync(deg, 0, (size_t)N * 4, stream);
    deg_kernel<<<nchunks, 256, 0, stream>>>(dst, deg, E);
    scan1<<<nb, 1024, 0, stream>>>(deg, offs, bsum, dis, N);
    scan2<<<1, 128, 0, stream>>>(bsum, bbase, nb);
    scan3<<<nb, 1024, 0, stream>>>(offs, bbase, cursor, N);
    cvt_w<<<(2 * F * F / 4 + 255) / 256, 256, 0, stream>>>(W1, W2, W1h, W2h);

    fill_xcd<<<nchunks * NXCD, 256, 0, stream>>>(src, dst, dis, cursor, edges,
                                                 E, prange, N);

    // layer 1: h = x @ W1.T (fp32 in, fp16 out), agg(+b1+lrelu) -> g (fp16)
    gemm_a32<<<gemm_grid, 256, 0, stream>>>(x, W1h, hh, ntiles);
    agg_to_h<<<(N + 3) / 4, 256, 0, stream>>>((const half8_t*)hh, dis, b1, edges,
                                              offs, (half8_t*)g, N, E);
    // layer 2: h = g @ W2.T (fp16), agg(+b2+lrelu) -> d_out (fp32)
    gemm_a16<<<gemm_grid, 256, 0, stream>>>(g, W2h, hh, ntiles);
    agg_to_f<<<(N + 3) / 4, 256, 0, stream>>>((const half8_t*)hh, dis, b2, edges,
                                              offs, out, N, E);
}

// Round 7
// 367.717 us; speedup vs baseline: 1.3201x; 1.2034x over previous
//
#include <hip/hip_runtime.h>

#define F 128
#define NEG_SLOPE 0.01f
#define NPB 256      // nodes per bucket (1<<8)
#define PMAX 512     // max buckets (LDS sizing); nP = ceil(N/256) = 391
#define HB 4096      // edges per hist block
#define BB 8192      // edges per bin block
#define CAP 6144     // csr LDS staging capacity (avg 4092; key-0 inputs << this)

typedef _Float16 half8_t __attribute__((ext_vector_type(8)));
typedef float f32x4 __attribute__((ext_vector_type(4)));

// ---------------- CSR build: two-level bucket sort ----------------
// Edge records pack to 4B: (dst_local<<17)|src  -- requires N < 131072.
// All scattered stores are LDS-staged so line-mates are written by one
// block, microseconds apart -> they merge in L2 (round-6 lesson: grid
// shaping can't fix temporal spread of line writers).

__global__ __launch_bounds__(256) void hist_kernel(const int* __restrict__ dst,
                                                   int* __restrict__ bcnt,
                                                   int E, int nP) {
    __shared__ int h[PMAX];
    int tid = threadIdx.x;
    for (int i = tid; i < nP; i += 256) h[i] = 0;
    __syncthreads();
    int base = blockIdx.x * HB;
    for (int i = tid; i < HB && base + i < E; i += 256)
        atomicAdd(&h[dst[base + i] >> 8], 1);
    __syncthreads();
    for (int i = tid; i < nP; i += 256)
        if (h[i]) atomicAdd(&bcnt[i], h[i]);
}

__global__ __launch_bounds__(512) void scan_bk(const int* __restrict__ bcnt,
                                               int* __restrict__ bbase,
                                               int* __restrict__ bcur, int nP) {
    __shared__ int s[512];
    int tid = threadIdx.x;
    int v = (tid < nP) ? bcnt[tid] : 0;
    int run = v;
    s[tid] = v;
    __syncthreads();
    for (int off = 1; off < 512; off <<= 1) {
        int add = (tid >= off) ? s[tid - off] : 0;
        __syncthreads();
        run += add;
        s[tid] = run;
        __syncthreads();
    }
    if (tid < nP) { bbase[tid] = run - v; bcur[tid] = run - v; }
}

__global__ __launch_bounds__(256) void bin_kernel(const int* __restrict__ src,
                                                  const int* __restrict__ dst,
                                                  int* __restrict__ bcur,
                                                  int* __restrict__ binned,
                                                  int E, int nP) {
    __shared__ int hist[PMAX];
    __shared__ int lbase[PMAX];
    __shared__ int gbase[PMAX];
    __shared__ int cur[PMAX];
    __shared__ int sa[PMAX];
    __shared__ int buf[BB];
    __shared__ unsigned short b16[BB];
    int tid = threadIdx.x;
    int base = blockIdx.x * BB;
    int myE = E - base; if (myE > BB) myE = BB;

    for (int i = tid; i < nP; i += 256) hist[i] = 0;
    __syncthreads();
    for (int i = tid; i < myE; i += 256)
        atomicAdd(&hist[dst[base + i] >> 8], 1);
    __syncthreads();
    // inclusive scan over PMAX entries, 2 per thread
    {
        int j0 = tid, j1 = tid + 256;
        sa[j0] = (j0 < nP) ? hist[j0] : 0;
        sa[j1] = (j1 < nP) ? hist[j1] : 0;
        __syncthreads();
        for (int off = 1; off < PMAX; off <<= 1) {
            int t0 = sa[j0] + (j0 >= off ? sa[j0 - off] : 0);
            int t1 = sa[j1] + (j1 >= off ? sa[j1 - off] : 0);
            __syncthreads();
            sa[j0] = t0; sa[j1] = t1;
            __syncthreads();
        }
        if (j0 < nP) { lbase[j0] = sa[j0] - hist[j0]; cur[j0] = sa[j0] - hist[j0]; }
        if (j1 < nP) { lbase[j1] = sa[j1] - hist[j1]; cur[j1] = sa[j1] - hist[j1]; }
    }
    __syncthreads();
    for (int i = tid; i < nP; i += 256)
        gbase[i] = hist[i] ? atomicAdd(&bcur[i], hist[i]) : 0;
    __syncthreads();
    // reorder into LDS, bucket-contiguous
    for (int i = tid; i < myE; i += 256) {
        int d = dst[base + i], s = src[base + i];
        int b = d >> 8;
        int lp = atomicAdd(&cur[b], 1);
        buf[lp] = ((d & (NPB - 1)) << 17) | s;
        b16[lp] = (unsigned short)b;
    }
    __syncthreads();
    // coalesced run writes
    for (int j = tid; j < myE; j += 256) {
        int b = b16[j];
        binned[gbase[b] + (j - lbase[b])] = buf[j];
    }
}

// one block per bucket: exact CSR + offs + dis (replaces deg/scan1/2/3/fill)
__global__ __launch_bounds__(256) void csr_kernel(const int* __restrict__ binned,
                                                  const int* __restrict__ bcnt,
                                                  const int* __restrict__ bbase,
                                                  int* __restrict__ srcs,
                                                  int* __restrict__ offs,
                                                  float* __restrict__ dis, int N) {
    __shared__ int cnt[NPB];
    __shared__ int tmp[NPB];
    __shared__ int cur[NPB];
    __shared__ int buf[CAP];
    int tid = threadIdx.x;
    int b = blockIdx.x;
    int ebase = bbase[b];
    int count = bcnt[b];
    int lo = b << 8;
    cnt[tid] = 0;
    __syncthreads();
    for (int j = tid; j < count; j += 256)
        atomicAdd(&cnt[binned[ebase + j] >> 17], 1);
    __syncthreads();
    int v = cnt[tid];
    int run = v;
    tmp[tid] = v;
    __syncthreads();
    for (int off = 1; off < 256; off <<= 1) {
        int add = (tid >= off) ? tmp[tid - off] : 0;
        __syncthreads();
        run += add;
        tmp[tid] = run;
        __syncthreads();
    }
    int excl = run - v;
    cur[tid] = excl;
    int node = lo + tid;
    if (node < N) {
        offs[node] = ebase + excl;
        dis[node] = rsqrtf((float)v + 1.0f);
    }
    __syncthreads();
    for (int j = tid; j < count; j += 256) {
        int rec = binned[ebase + j];
        int pos = atomicAdd(&cur[rec >> 17], 1);
        int s = rec & 0x1FFFF;
        if (pos < CAP) buf[pos] = s; else srcs[ebase + pos] = s;
    }
    __syncthreads();
    int lim = count < CAP ? count : CAP;
    for (int j = tid; j < lim; j += 256)
        srcs[ebase + j] = buf[j];
}

// ---------------- W1+W2 fp32 -> fp16 in one launch ----------------

__global__ __launch_bounds__(256) void cvt_w(const float* __restrict__ W1,
                                             const float* __restrict__ W2,
                                             _Float16* __restrict__ W1h,
                                             _Float16* __restrict__ W2h) {
    int i = blockIdx.x * 256 + threadIdx.x;       // 0 .. 8191 (2 * 128*128/4)
    const int n4 = F * F / 4;
    const float* in = (i < n4) ? W1 : W2;
    _Float16* out = (i < n4) ? W1h : W2h;
    int j = (i < n4) ? i : i - n4;
    float4 v = ((const float4*)in)[j];
    half8_t h;  // only low 4 used
    h[0] = (_Float16)v.x; h[1] = (_Float16)v.y;
    h[2] = (_Float16)v.z; h[3] = (_Float16)v.w;
    *(int2*)&((_Float16*)out)[j * 4] = *(int2*)&h;
}

// ---------------- GEMM: out = A @ W.T via f16 MFMA ----------------
// Layouts: A[m=lane&15][k=quad*8+j]; B[n=lane&15][k=quad*8+j] (=W[n][k]);
// C/D: col=lane&15, row=quad*4+reg.

__device__ __forceinline__ void gemm_core(const half8_t afrag[4],
                                          const _Float16* __restrict__ Wh,
                                          int m, int quad,
                                          _Float16* __restrict__ orow) {
    f32x4 acc[8];
#pragma unroll
    for (int t = 0; t < 8; ++t) acc[t] = (f32x4){0.f, 0.f, 0.f, 0.f};
#pragma unroll
    for (int c = 0; c < 4; ++c) {
#pragma unroll
        for (int t = 0; t < 8; ++t) {
            half8_t bfrag = *(const half8_t*)&Wh[(t * 16 + m) * F + c * 32 + quad * 8];
            acc[t] = __builtin_amdgcn_mfma_f32_16x16x32_f16(afrag[c], bfrag, acc[t],
                                                            0, 0, 0);
        }
    }
#pragma unroll
    for (int t = 0; t < 8; ++t)
#pragma unroll
        for (int r = 0; r < 4; ++r)
            orow[(quad * 4 + r) * F + t * 16 + m] = (_Float16)acc[t][r];
}

__global__ __launch_bounds__(256) void gemm_a32(const float* __restrict__ A,
                                                const _Float16* __restrict__ Wh,
                                                _Float16* __restrict__ out,
                                                int ntiles) {
    int wave = threadIdx.x >> 6;
    int lane = threadIdx.x & 63;
    int tile = blockIdx.x * 4 + wave;
    if (tile >= ntiles) return;
    int m = lane & 15, quad = lane >> 4;
    const float* arow = A + (size_t)tile * 16 * F;
    half8_t afrag[4];
#pragma unroll
    for (int c = 0; c < 4; ++c) {
        float4 t0 = *(const float4*)&arow[m * F + c * 32 + quad * 8];
        float4 t1 = *(const float4*)&arow[m * F + c * 32 + quad * 8 + 4];
        afrag[c][0] = (_Float16)t0.x; afrag[c][1] = (_Float16)t0.y;
        afrag[c][2] = (_Float16)t0.z; afrag[c][3] = (_Float16)t0.w;
        afrag[c][4] = (_Float16)t1.x; afrag[c][5] = (_Float16)t1.y;
        afrag[c][6] = (_Float16)t1.z; afrag[c][7] = (_Float16)t1.w;
    }
    gemm_core(afrag, Wh, m, quad, out + (size_t)tile * 16 * F);
}

__global__ __launch_bounds__(256) void gemm_a16(const _Float16* __restrict__ A,
                                                const _Float16* __restrict__ Wh,
                                                _Float16* __restrict__ out,
                                                int ntiles) {
    int wave = threadIdx.x >> 6;
    int lane = threadIdx.x & 63;
    int tile = blockIdx.x * 4 + wave;
    if (tile >= ntiles) return;
    int m = lane & 15, quad = lane >> 4;
    const _Float16* arow = A + (size_t)tile * 16 * F;
    half8_t afrag[4];
#pragma unroll
    for (int c = 0; c < 4; ++c)
        afrag[c] = *(const half8_t*)&arow[m * F + c * 32 + quad * 8];
    gemm_core(afrag, Wh, m, quad, out + (size_t)tile * 16 * F);
}

// ---------------- aggregation ----------------
// One wave per node; 16 lanes x half8 cover one 256B row; 4 edge groups.
// 4B CSR records (src only); norm = dis[src] (L2-resident table) folded
// with wave-uniform dis[node] AFTER the cross-lane reduce.

#define AGG_BODY(H8)                                                           \
    int node = blockIdx.x * 4 + (threadIdx.x >> 6);                            \
    int lane = threadIdx.x & 63;                                               \
    if (node >= n) return;                                                     \
    int g = lane >> 4;                                                         \
    int fo = lane & 15;                                                        \
    int beg = offs[node];                                                      \
    int end = (node + 1 < n) ? offs[node + 1] : E;                             \
    float acc[8];                                                              \
    _Pragma("unroll") for (int j = 0; j < 8; ++j) acc[j] = 0.f;                \
    for (int e = beg; e < end; e += 8) {                                       \
        int i0 = e + g, i1 = e + 4 + g;                                        \
        int s0 = srcs[i0 < end ? i0 : end - 1];                                \
        int s1 = srcs[i1 < end ? i1 : end - 1];                                \
        float w0 = (i0 < end) ? dis[s0] : 0.f;                                 \
        float w1 = (i1 < end) ? dis[s1] : 0.f;                                 \
        half8_t a0 = H8[(size_t)s0 * 16 + fo];                                 \
        half8_t a1 = H8[(size_t)s1 * 16 + fo];                                 \
        _Pragma("unroll") for (int j = 0; j < 8; ++j)                          \
            acc[j] += w0 * (float)a0[j] + w1 * (float)a1[j];                   \
    }                                                                          \
    _Pragma("unroll") for (int j = 0; j < 8; ++j) {                            \
        acc[j] += __shfl_xor(acc[j], 16);                                      \
        acc[j] += __shfl_xor(acc[j], 32);                                      \
    }                                                                          \
    if (lane >= 16) return;                                                    \
    float di = dis[node];                                                      \
    float sw = di * di;                                                        \
    half8_t hv = H8[(size_t)node * 16 + fo];                                   \
    float4 b0 = ((const float4*)bias)[fo * 2];                                 \
    float4 b1v = ((const float4*)bias)[fo * 2 + 1];                            \
    acc[0] = di * acc[0] + sw * (float)hv[0] + b0.x;                           \
    acc[1] = di * acc[1] + sw * (float)hv[1] + b0.y;                           \
    acc[2] = di * acc[2] + sw * (float)hv[2] + b0.z;                           \
    acc[3] = di * acc[3] + sw * (float)hv[3] + b0.w;                           \
    acc[4] = di * acc[4] + sw * (float)hv[4] + b1v.x;                          \
    acc[5] = di * acc[5] + sw * (float)hv[5] + b1v.y;                          \
    acc[6] = di * acc[6] + sw * (float)hv[6] + b1v.z;                          \
    acc[7] = di * acc[7] + sw * (float)hv[7] + b1v.w;                          \
    _Pragma("unroll") for (int j = 0; j < 8; ++j)                              \
        acc[j] = (acc[j] > 0.f) ? acc[j] : acc[j] * NEG_SLOPE;

__global__ __launch_bounds__(256) void agg_to_h(const half8_t* __restrict__ h8,
                                                const float* __restrict__ dis,
                                                const float* __restrict__ bias,
                                                const int* __restrict__ srcs,
                                                const int* __restrict__ offs,
                                                half8_t* __restrict__ out,
                                                int n, int E) {
    AGG_BODY(h8)
    half8_t o;
#pragma unroll
    for (int j = 0; j < 8; ++j) o[j] = (_Float16)acc[j];
    out[(size_t)node * 16 + fo] = o;
}

__global__ __launch_bounds__(256) void agg_to_f(const half8_t* __restrict__ h8,
                                                const float* __restrict__ dis,
                                                const float* __restrict__ bias,
                                                const int* __restrict__ srcs,
                                                const int* __restrict__ offs,
                                                float* __restrict__ out,
                                                int n, int E) {
    AGG_BODY(h8)
    float4 o0 = make_float4(acc[0], acc[1], acc[2], acc[3]);
    float4 o1 = make_float4(acc[4], acc[5], acc[6], acc[7]);
    ((float4*)out)[(size_t)node * 32 + fo * 2] = o0;
    ((float4*)out)[(size_t)node * 32 + fo * 2 + 1] = o1;
}

// ---------------- launch ----------------

static inline size_t alup(size_t x) { return (x + 255) & ~(size_t)255; }

extern "C" void kernel_launch(void* const* d_in, const int* in_sizes, int n_in,
                              void* d_out, int out_size, void* d_ws, size_t ws_size,
                              hipStream_t stream) {
    const float* x  = (const float*)d_in[0];
    const int*   ei = (const int*)d_in[1];
    const float* W1 = (const float*)d_in[2];
    const float* b1 = (const float*)d_in[3];
    const float* W2 = (const float*)d_in[4];
    const float* b2 = (const float*)d_in[5];
    float* out = (float*)d_out;

    const int N = in_sizes[0] / F;    // 100000  (< 2^17 for 4B packing)
    const int E = in_sizes[1] / 2;    // 1600000
    const int* src = ei;
    const int* dst = ei + E;

    char* p = (char*)d_ws;
    int*      bcnt   = (int*)p;      p += alup(PMAX * 4);
    int*      bbase  = (int*)p;      p += alup(PMAX * 4);
    int*      bcur   = (int*)p;      p += alup(PMAX * 4);
    float*    dis    = (float*)p;    p += alup((size_t)N * 4);
    int*      offs   = (int*)p;      p += alup((size_t)N * 4);
    int*      binned = (int*)p;      p += alup((size_t)E * 4);
    int*      srcs   = (int*)p;      p += alup((size_t)E * 4);
    _Float16* g      = (_Float16*)p; p += alup((size_t)N * F * 2);
    _Float16* hh     = (_Float16*)p; p += alup((size_t)N * F * 2);
    _Float16* W1h    = (_Float16*)p; p += alup((size_t)F * F * 2);
    _Float16* W2h    = (_Float16*)p; p += alup((size_t)F * F * 2);

    const int nP = (N + NPB - 1) / NPB;        // 391
    const int ntiles = (N + 15) / 16;          // 6250
    const int gemm_grid = (ntiles + 3) / 4;

    hipMemsetAsync(bcnt, 0, PMAX * 4, stream);
    hist_kernel<<<(E + HB - 1) / HB, 256, 0, stream>>>(dst, bcnt, E, nP);
    scan_bk<<<1, 512, 0, stream>>>(bcnt, bbase, bcur, nP);
    bin_kernel<<<(E + BB - 1) / BB, 256, 0, stream>>>(src, dst, bcur, binned, E, nP);
    csr_kernel<<<nP, 256, 0, stream>>>(binned, bcnt, bbase, srcs, offs, dis, N);
    cvt_w<<<(2 * F * F / 4 + 255) / 256, 256, 0, stream>>>(W1, W2, W1h, W2h);

    // layer 1: h = x @ W1.T (fp32 in, fp16 out), agg(+b1+lrelu) -> g (fp16)
    gemm_a32<<<gemm_grid, 256, 0, stream>>>(x, W1h, hh, ntiles);
    agg_to_h<<<(N + 3) / 4, 256, 0, stream>>>((const half8_t*)hh, dis, b1, srcs,
                                              offs, (half8_t*)g, N, E);
    // layer 2: h = g @ W2.T (fp16), agg(+b2+lrelu) -> d_out (fp32)
    gemm_a16<<<gemm_grid, 256, 0, stream>>>(g, W2h, hh, ntiles);
    agg_to_f<<<(N + 3) / 4, 256, 0, stream>>>((const half8_t*)hh, dis, b2, srcs,
                                              offs, out, N, E);
}